// Round 1
// baseline (279.711 us; speedup 1.0000x reference)
//
#include <hip/hip_runtime.h>

// SosModel: y = cascade of 4 biquads (direct-form-I) over time, per (batch,channel).
// B=16, T=32768, C=64, S=4. Poles are stable (r in [0.5,0.9]) -> overlap-save:
// each wave handles one (batch, time-chunk); warm-up WARM steps from zero state
// makes the truncated transient ~0.9^320 ~ 2e-15 (negligible vs 2.6e-2 threshold).
// lane == channel (C==64==wavefront) -> every step's load/store is one contiguous
// 256B row: perfectly coalesced.

#define TLEN  32768
#define CCH   64
#define BATCH 16
#define NSEC  4
#define CHUNK 256   // output timesteps per wave
#define WARM  320   // warm-up steps (discarded); 0.9^320*320^3 ~ 6e-8

#define NCHUNKS (TLEN / CHUNK)          // 128
#define NWAVES  (BATCH * NCHUNKS)       // 2048
#define BLOCK   256
#define NBLOCKS (NWAVES * 64 / BLOCK)   // 512

__global__ __launch_bounds__(BLOCK) void sos_kernel(const float* __restrict__ x,
                                                    const float* __restrict__ sos,
                                                    float* __restrict__ out) {
    const int lane = threadIdx.x & 63;                       // channel
    const int wid  = blockIdx.x * (BLOCK >> 6) + (threadIdx.x >> 6);
    const int b    = wid / NCHUNKS;
    const int k    = wid - b * NCHUNKS;
    const int t0   = k * CHUNK;
    const int s0   = (t0 >= WARM) ? (t0 - WARM) : 0;
    const int warm = t0 - s0;                                 // 0 (chunk 0) / 256 (chunk 1) / 320

    // Coefficients (uniform -> scalar loads). a0 == 1 in this dataset, but honor /a0.
    float c_b0[NSEC], c_b1[NSEC], c_b2[NSEC], c_a1n[NSEC], c_a2n[NSEC];
    float xx1[NSEC], xx2[NSEC], yy1[NSEC], yy2[NSEC];
#pragma unroll
    for (int s = 0; s < NSEC; ++s) {
        const float inva = 1.0f / sos[s * 6 + 3];
        c_b0[s]  =  sos[s * 6 + 0] * inva;
        c_b1[s]  =  sos[s * 6 + 1] * inva;
        c_b2[s]  =  sos[s * 6 + 2] * inva;
        c_a1n[s] = -sos[s * 6 + 4] * inva;
        c_a2n[s] = -sos[s * 6 + 5] * inva;
        xx1[s] = xx2[s] = yy1[s] = yy2[s] = 0.0f;
    }

    const float* __restrict__ px = x   + ((size_t)b * TLEN + (size_t)s0) * CCH + lane;
    float*       __restrict__ py = out + ((size_t)b * TLEN + (size_t)t0) * CCH + lane;

    // Warm-up: run the filter, discard outputs. warm is wave-uniform (no divergence).
#pragma unroll 8
    for (int t = 0; t < warm; ++t) {
        float acc = *px; px += CCH;
#pragma unroll
        for (int s = 0; s < NSEC; ++s) {
            float y = fmaf(c_b0[s], acc,
                      fmaf(c_b1[s], xx1[s],
                      fmaf(c_b2[s], xx2[s],
                      fmaf(c_a1n[s], yy1[s], c_a2n[s] * yy2[s]))));
            xx2[s] = xx1[s]; xx1[s] = acc;
            yy2[s] = yy1[s]; yy1[s] = y;
            acc = y;
        }
    }

    // Main: CHUNK steps, store each output row (coalesced 256B per wave per step).
#pragma unroll 8
    for (int t = 0; t < CHUNK; ++t) {
        float acc = *px; px += CCH;
#pragma unroll
        for (int s = 0; s < NSEC; ++s) {
            float y = fmaf(c_b0[s], acc,
                      fmaf(c_b1[s], xx1[s],
                      fmaf(c_b2[s], xx2[s],
                      fmaf(c_a1n[s], yy1[s], c_a2n[s] * yy2[s]))));
            xx2[s] = xx1[s]; xx1[s] = acc;
            yy2[s] = yy1[s]; yy1[s] = y;
            acc = y;
        }
        *py = acc; py += CCH;
    }
}

extern "C" void kernel_launch(void* const* d_in, const int* in_sizes, int n_in,
                              void* d_out, int out_size, void* d_ws, size_t ws_size,
                              hipStream_t stream) {
    const float* x   = (const float*)d_in[0];   // [B, T, C] fp32
    const float* sos = (const float*)d_in[1];   // [S, 6] fp32
    float* out = (float*)d_out;                 // [B, T, C] fp32
    sos_kernel<<<NBLOCKS, BLOCK, 0, stream>>>(x, sos, out);
}

// Round 2
// 259.480 us; speedup vs baseline: 1.0780x; 1.0780x over previous
//
#include <hip/hip_runtime.h>

// SosModel: cascade of 4 biquads over T=32768, per (batch,channel); B=16, C=64.
// Overlap-save: each wave = one (batch, 128-step chunk), WARM=128 warm-up from
// zero state (stable poles r<=0.9 -> truncation ~0.9^128*gain ~ 1e-4 << 2.6e-2).
// lane == channel -> one contiguous 256B row load/store per wave per step.
//
// Skewed-pipeline cascade: at iteration i, section s processes time s0+i-s.
// The 4 section updates are independent within an iteration; loop-carried
// dependency is 1 FMA per section (y1 -> y). Output delayed SKEW=3 steps.
//
// Software-pipelined loads: group-of-8, next group's 8 row-loads issued
// before computing the current group (>=8 loads in flight per wave).

#define TLEN  32768
#define CCH   64
#define BATCH 16
#define NSEC  4
#define CHUNK 128
#define WARM  128
#define SKEW  3          // NSEC-1 pipeline delay

#define NCHUNKS (TLEN / CHUNK)          // 256
#define NWAVES  (BATCH * NCHUNKS)       // 4096
#define BLOCK   256
#define NBLOCKS (NWAVES * 64 / BLOCK)   // 1024  -> 4 blocks/CU, 16 waves/CU

__global__ __launch_bounds__(BLOCK, 4) void sos_kernel(const float* __restrict__ x,
                                                       const float* __restrict__ sos,
                                                       float* __restrict__ out) {
    const int lane = threadIdx.x & 63;                      // channel
    const int wid  = blockIdx.x * (BLOCK >> 6) + (threadIdx.x >> 6);
    const int b    = wid >> 8;                              // wid / NCHUNKS
    const int k    = wid & (NCHUNKS - 1);
    const int t0   = k * CHUNK;
    const int s0   = (t0 >= WARM) ? (t0 - WARM) : 0;
    const int warm = t0 - s0;                               // 0 (chunk 0) or 128

    // Coefficients (wave-uniform scalar loads); honor /a0 though a0==1 here.
    float cb0[NSEC], cb1[NSEC], cb2[NSEC], ca1[NSEC], ca2[NSEC];
    float x1[NSEC], x2[NSEC], y1v[NSEC], y2v[NSEC];
#pragma unroll
    for (int s = 0; s < NSEC; ++s) {
        const float inva = 1.0f / sos[s * 6 + 3];
        cb0[s] =  sos[s * 6 + 0] * inva;
        cb1[s] =  sos[s * 6 + 1] * inva;
        cb2[s] =  sos[s * 6 + 2] * inva;
        ca1[s] = -sos[s * 6 + 4] * inva;
        ca2[s] = -sos[s * 6 + 5] * inva;
        x1[s] = x2[s] = y1v[s] = y2v[s] = 0.0f;
    }
    float lat1 = 0.0f, lat2 = 0.0f, lat3 = 0.0f;   // inter-section pipeline latches

    const float* __restrict__ xb = x + (size_t)b * TLEN * CCH + lane;
    float* __restrict__ py = out + ((size_t)b * TLEN + (size_t)t0) * CCH + lane;

    const int total  = warm + CHUNK + SKEW;         // 131 or 259
    const int padded = (total + 7) & ~7;            // 136 or 264 (extra iters read clamped, no store)
    const int sfrom  = warm + SKEW;                 // first iteration whose output we keep

    // Prime the load pipeline with the first 8 input rows.
    float xbuf[8];
#pragma unroll
    for (int j = 0; j < 8; ++j) {
        int idx = s0 + j; if (idx > TLEN - 1) idx = TLEN - 1;
        xbuf[j] = xb[(size_t)idx * CCH];
    }

    for (int g = 0; g < padded; g += 8) {
        // Issue next group's loads before computing this group.
        float nbuf[8];
#pragma unroll
        for (int j = 0; j < 8; ++j) {
            int idx = s0 + g + 8 + j; if (idx > TLEN - 1) idx = TLEN - 1;
            nbuf[j] = xb[(size_t)idx * CCH];
        }
#pragma unroll
        for (int j = 0; j < 8; ++j) {
            const int i = g + j;
            const float i0 = xbuf[j], i1 = lat1, i2 = lat2, i3 = lat3;
            // Feed-forward parts (no loop-carried accumulation through these).
            const float p0 = fmaf(cb0[0], i0, fmaf(cb1[0], x1[0], cb2[0] * x2[0]));
            const float p1 = fmaf(cb0[1], i1, fmaf(cb1[1], x1[1], cb2[1] * x2[1]));
            const float p2 = fmaf(cb0[2], i2, fmaf(cb1[2], x1[2], cb2[2] * x2[2]));
            const float p3 = fmaf(cb0[3], i3, fmaf(cb1[3], x1[3], cb2[3] * x2[3]));
            // Recurrent parts: y1 -> o is the only 1-iteration-distance FMA.
            const float o0 = fmaf(ca1[0], y1v[0], fmaf(ca2[0], y2v[0], p0));
            const float o1 = fmaf(ca1[1], y1v[1], fmaf(ca2[1], y2v[1], p1));
            const float o2 = fmaf(ca1[2], y1v[2], fmaf(ca2[2], y2v[2], p2));
            const float o3 = fmaf(ca1[3], y1v[3], fmaf(ca2[3], y2v[3], p3));
            x2[0] = x1[0]; x1[0] = i0;  y2v[0] = y1v[0]; y1v[0] = o0;
            x2[1] = x1[1]; x1[1] = i1;  y2v[1] = y1v[1]; y1v[1] = o1;
            x2[2] = x1[2]; x1[2] = i2;  y2v[2] = y1v[2]; y1v[2] = o2;
            x2[3] = x1[3]; x1[3] = i3;  y2v[3] = y1v[3]; y1v[3] = o3;
            lat1 = o0; lat2 = o1; lat3 = o2;
            if (i >= sfrom && i < total) {              // wave-uniform guard
                py[(size_t)(i - sfrom) * CCH] = o3;
            }
        }
#pragma unroll
        for (int j = 0; j < 8; ++j) xbuf[j] = nbuf[j];
    }
}

extern "C" void kernel_launch(void* const* d_in, const int* in_sizes, int n_in,
                              void* d_out, int out_size, void* d_ws, size_t ws_size,
                              hipStream_t stream) {
    const float* x   = (const float*)d_in[0];   // [B, T, C] fp32
    const float* sos = (const float*)d_in[1];   // [S, 6] fp32
    float* out = (float*)d_out;                 // [B, T, C] fp32
    sos_kernel<<<NBLOCKS, BLOCK, 0, stream>>>(x, sos, out);
}